// Round 4
// baseline (1447.093 us; speedup 1.0000x reference)
//
#include <hip/hip_runtime.h>
#include <cstdint>
#include <cstddef>

#define B_ 32
#define T_ 2048
#define D_ 128
#define U_ 128
#define G4_ 512
#define P1_ROWS 32

typedef _Float16 f16x8 __attribute__((ext_vector_type(8)));
typedef float f32x4 __attribute__((ext_vector_type(4)));

__device__ __forceinline__ float sigf(float z) {
  return __builtin_amdgcn_rcpf(1.f + __expf(-z));
}
__device__ __forceinline__ float tanhf_(float z) {
  return 2.f * __builtin_amdgcn_rcpf(1.f + __expf(-2.f * z)) - 1.f;
}

// Phase 1: Zx[b][col][t] = bias[col] + sum_k x[b,t,k] * Wx[k][col]
__global__ __launch_bounds__(512)
void zx_kernel(const float* __restrict__ x, const float* __restrict__ Wx,
               const float* __restrict__ bias, float* __restrict__ Zx,
               int tbase, int ct) {
  const int j = threadIdx.x;
  const int nt = ct / P1_ROWS;
  const int tblk = blockIdx.x % nt;
  const int b = blockIdx.x / nt;
  const int t0 = tblk * P1_ROWS;

  __shared__ float xsT[D_ * P1_ROWS];  // transposed: [k][r]

  const float* xp = x + ((size_t)b * T_ + tbase + t0) * D_;
  {
    int e = j * 8;
    int r = e >> 7;
    int k = e & 127;
    float4 v0 = *(const float4*)(xp + e);
    float4 v1 = *(const float4*)(xp + e + 4);
    xsT[(k + 0) * P1_ROWS + r] = v0.x;
    xsT[(k + 1) * P1_ROWS + r] = v0.y;
    xsT[(k + 2) * P1_ROWS + r] = v0.z;
    xsT[(k + 3) * P1_ROWS + r] = v0.w;
    xsT[(k + 4) * P1_ROWS + r] = v1.x;
    xsT[(k + 5) * P1_ROWS + r] = v1.y;
    xsT[(k + 6) * P1_ROWS + r] = v1.z;
    xsT[(k + 7) * P1_ROWS + r] = v1.w;
  }
  __syncthreads();

  const float bj = bias[j];
  float acc[P1_ROWS];
#pragma unroll
  for (int r = 0; r < P1_ROWS; ++r) acc[r] = bj;

  const float* wp = Wx + j;
  float w = wp[0];
#pragma unroll 2
  for (int k = 0; k < D_; ++k) {
    float wn = (k + 1 < D_) ? wp[(size_t)(k + 1) * G4_] : 0.f;
    const float4* xr = (const float4*)(xsT + k * P1_ROWS);
#pragma unroll
    for (int r4 = 0; r4 < P1_ROWS / 4; ++r4) {
      float4 xv = xr[r4];
      acc[4 * r4 + 0] += xv.x * w;
      acc[4 * r4 + 1] += xv.y * w;
      acc[4 * r4 + 2] += xv.z * w;
      acc[4 * r4 + 3] += xv.w * w;
    }
    w = wn;
  }

  float* zp = Zx + ((size_t)b * G4_ + j) * ct + t0;  // [b][col][t], t-contiguous
#pragma unroll
  for (int q = 0; q < P1_ROWS / 4; ++q)
    ((float4*)zp)[q] = make_float4(acc[4 * q], acc[4 * q + 1], acc[4 * q + 2], acc[4 * q + 3]);
}

// Phase 2: serial recurrence via f16 MFMA. One block (8 waves) per batch.
// Wave w owns u in [16w, 16w+16); its 4 N-tiles are the 4 gates of those u.
// A-frag = h broadcast (all 16 rows identical) -> any C row is z.
// Lane (col = lane&15) holds i,f,g,o of its u in its accumulators.
// In-loop barrier is raw s_barrier + lgkmcnt(0) only: out[] stores and Zx
// prefetch loads stay outstanding across the barrier (not in the chain).
__global__ __launch_bounds__(512)
void lstm_kernel(const float* __restrict__ Zx, const float* __restrict__ Wh,
                 float* __restrict__ out, float* __restrict__ state,
                 int tbase, int ct, int first) {
  const int j = threadIdx.x;
  const int b = blockIdx.x;
  const int w = j >> 6;
  const int lane = j & 63;
  const int l4 = lane & 15;
  const int kg = lane >> 4;       // k-group 0..3
  const int u = w * 16 + l4;      // duplicated across kg groups

  // B fragments: Wh[k][col], col = g*128+u, k = kt*32 + kg*8 + e (f32 -> f16)
  f16x8 bf[4][4];
#pragma unroll
  for (int g = 0; g < 4; ++g)
#pragma unroll
    for (int kt = 0; kt < 4; ++kt) {
      f16x8 v;
#pragma unroll
      for (int e = 0; e < 8; ++e)
        v[e] = (_Float16)Wh[(size_t)(kt * 32 + kg * 8 + e) * G4_ + g * U_ + u];
      bf[g][kt] = v;
    }

  __shared__ alignas(16) _Float16 hbuf[2][U_];  // double-buffered h (f16)

  float c_state = 0.f, h0 = 0.f;
  if (!first) {
    h0 = state[b * 2 * U_ + u];
    c_state = state[b * 2 * U_ + U_ + u];
  }
  if (kg == 0) hbuf[0][u] = (_Float16)h0;
  __syncthreads();

  const float4* zq0 = (const float4*)(Zx + ((size_t)b * G4_ + 0 * U_ + u) * ct);
  const float4* zq1 = (const float4*)(Zx + ((size_t)b * G4_ + 1 * U_ + u) * ct);
  const float4* zq2 = (const float4*)(Zx + ((size_t)b * G4_ + 2 * U_ + u) * ct);
  const float4* zq3 = (const float4*)(Zx + ((size_t)b * G4_ + 3 * U_ + u) * ct);

  float4 zc0 = zq0[0], zc1 = zq1[0], zc2 = zq2[0], zc3 = zq3[0];
  float hlast = h0;
  float* outp = out + ((size_t)tbase * B_ + b) * U_ + u;

  // Persistent accumulators: only element 0 is ever consumed; rows 1-3 carry
  // bounded garbage (broadcast-A rows are identical, so they grow by the same
  // finite dot each step — no overflow, never read).
  f32x4 accA0 = {0.f, 0.f, 0.f, 0.f}, accA1 = accA0, accA2 = accA0, accA3 = accA0;
  f32x4 accB0 = accA0, accB1 = accA0, accB2 = accA0, accB3 = accA0;

  for (int tt = 0; tt < ct; tt += 4) {
    float4 zn0, zn1, zn2, zn3;
    if (tt + 4 < ct) {
      const int nq = (tt >> 2) + 1;
      zn0 = zq0[nq]; zn1 = zq1[nq]; zn2 = zq2[nq]; zn3 = zq3[nq];
    } else {
      zn0 = zn1 = zn2 = zn3 = make_float4(0.f, 0.f, 0.f, 0.f);
    }
#pragma unroll
    for (int s = 0; s < 4; ++s) {
      const int t = tt + s;
      const int cur = t & 1;
      const float zi0 = (s == 0) ? zc0.x : (s == 1) ? zc0.y : (s == 2) ? zc0.z : zc0.w;
      const float zi1 = (s == 0) ? zc1.x : (s == 1) ? zc1.y : (s == 2) ? zc1.z : zc1.w;
      const float zi2 = (s == 0) ? zc2.x : (s == 1) ? zc2.y : (s == 2) ? zc2.z : zc2.w;
      const float zi3 = (s == 0) ? zc3.x : (s == 1) ? zc3.y : (s == 2) ? zc3.z : zc3.w;

      // A-frags: broadcast h slice per k-group (16B per kt), in use order
      const f16x8* hp = (const f16x8*)hbuf[cur];
      f16x8 a0 = hp[0 * 4 + kg];
      f16x8 a2 = hp[2 * 4 + kg];
      f16x8 a1 = hp[1 * 4 + kg];
      f16x8 a3 = hp[3 * 4 + kg];

      // per-step init: only element 0 matters
      accA0[0] = zi0; accA1[0] = zi1; accA2[0] = zi2; accA3[0] = zi3;
      accB0[0] = 0.f; accB1[0] = 0.f; accB2[0] = 0.f; accB3[0] = 0.f;

      // 8 independent chains, depth 2 each
      accA0 = __builtin_amdgcn_mfma_f32_16x16x32_f16(a0, bf[0][0], accA0, 0, 0, 0);
      accA1 = __builtin_amdgcn_mfma_f32_16x16x32_f16(a0, bf[1][0], accA1, 0, 0, 0);
      accA2 = __builtin_amdgcn_mfma_f32_16x16x32_f16(a0, bf[2][0], accA2, 0, 0, 0);
      accA3 = __builtin_amdgcn_mfma_f32_16x16x32_f16(a0, bf[3][0], accA3, 0, 0, 0);
      accB0 = __builtin_amdgcn_mfma_f32_16x16x32_f16(a2, bf[0][2], accB0, 0, 0, 0);
      accB1 = __builtin_amdgcn_mfma_f32_16x16x32_f16(a2, bf[1][2], accB1, 0, 0, 0);
      accB2 = __builtin_amdgcn_mfma_f32_16x16x32_f16(a2, bf[2][2], accB2, 0, 0, 0);
      accB3 = __builtin_amdgcn_mfma_f32_16x16x32_f16(a2, bf[3][2], accB3, 0, 0, 0);
      accA0 = __builtin_amdgcn_mfma_f32_16x16x32_f16(a1, bf[0][1], accA0, 0, 0, 0);
      accA1 = __builtin_amdgcn_mfma_f32_16x16x32_f16(a1, bf[1][1], accA1, 0, 0, 0);
      accA2 = __builtin_amdgcn_mfma_f32_16x16x32_f16(a1, bf[2][1], accA2, 0, 0, 0);
      accA3 = __builtin_amdgcn_mfma_f32_16x16x32_f16(a1, bf[3][1], accA3, 0, 0, 0);
      accB0 = __builtin_amdgcn_mfma_f32_16x16x32_f16(a3, bf[0][3], accB0, 0, 0, 0);
      accB1 = __builtin_amdgcn_mfma_f32_16x16x32_f16(a3, bf[1][3], accB1, 0, 0, 0);
      accB2 = __builtin_amdgcn_mfma_f32_16x16x32_f16(a3, bf[2][3], accB2, 0, 0, 0);
      accB3 = __builtin_amdgcn_mfma_f32_16x16x32_f16(a3, bf[3][3], accB3, 0, 0, 0);

      float i_ = sigf(accA0[0] + accB0[0]);
      float f_ = sigf(accA1[0] + accB1[0]);
      float g_ = tanhf_(accA2[0] + accB2[0]);
      float o_ = sigf(accA3[0] + accB3[0]);
      c_state = fmaf(f_, c_state, i_ * g_);
      float hn = o_ * tanhf_(c_state);
      hlast = hn;

      if (kg == 0) {
        outp[(size_t)t * B_ * U_] = hn;
        hbuf[cur ^ 1][u] = (_Float16)hn;
      }
      // LDS-only drain: out[] stores / Zx loads stay in flight
      asm volatile("s_waitcnt lgkmcnt(0)\n\ts_barrier" ::: "memory");
    }
    zc0 = zn0; zc1 = zn1; zc2 = zn2; zc3 = zn3;
  }

  if (kg == 0) {
    state[b * 2 * U_ + u] = hlast;
    state[b * 2 * U_ + U_ + u] = c_state;
  }
}

extern "C" void kernel_launch(void* const* d_in, const int* in_sizes, int n_in,
                              void* d_out, int out_size, void* d_ws, size_t ws_size,
                              hipStream_t stream) {
  const float* x = (const float*)d_in[0];
  const float* Wx = (const float*)d_in[1];
  const float* Wh = (const float*)d_in[2];
  const float* bias = (const float*)d_in[3];
  float* out = (float*)d_out;

  // ws layout: [0,32KB) = h/c carry state, rest = Zx chunk buffer
  float* state = (float*)d_ws;
  float* zx = (float*)((char*)d_ws + 32768);
  size_t avail = ws_size > 32768 ? ws_size - 32768 : 0;
  size_t per_t = (size_t)B_ * G4_ * sizeof(float);  // 64 KB per timestep
  long maxct = (long)(avail / per_t);
  int ct;
  if (maxct >= T_) ct = T_;
  else {
    ct = (int)((maxct / P1_ROWS) * P1_ROWS);
    if (ct < P1_ROWS) ct = P1_ROWS;
  }

  for (int tb = 0; tb < T_; tb += ct) {
    int cur = (T_ - tb < ct) ? (T_ - tb) : ct;
    zx_kernel<<<dim3(B_ * (cur / P1_ROWS)), 512, 0, stream>>>(x, Wx, bias, zx, tb, cur);
    lstm_kernel<<<dim3(B_), 512, 0, stream>>>(zx, Wh, out, state, tb, cur, tb == 0 ? 1 : 0);
  }
}

// Round 5
// 1166.416 us; speedup vs baseline: 1.2406x; 1.2406x over previous
//
#include <hip/hip_runtime.h>
#include <cstdint>
#include <cstddef>

#define B_ 32
#define T_ 2048
#define D_ 128
#define U_ 128
#define G4_ 512
#define P1_ROWS 32

typedef _Float16 f16x8 __attribute__((ext_vector_type(8)));
typedef float f32x4 __attribute__((ext_vector_type(4)));

__device__ __forceinline__ float sigf(float z) {
  return __builtin_amdgcn_rcpf(1.f + __expf(-z));
}
__device__ __forceinline__ float tanhf_(float z) {
  return 2.f * __builtin_amdgcn_rcpf(1.f + __expf(-2.f * z)) - 1.f;
}

// LDS-visibility-only barrier: waits for this wave's ds ops, then syncs the
// block. Crucially does NOT drain vmcnt — out[] stores and Zx prefetch loads
// stay in flight across it (compiler inserts counted vmcnt before Zx use).
// sched_barrier(0) pins ds_write/ds_read ordering without a memory clobber.
__device__ __forceinline__ void lds_barrier() {
  __builtin_amdgcn_sched_barrier(0);
  asm volatile("s_waitcnt lgkmcnt(0)");
  __builtin_amdgcn_sched_barrier(0);
  __builtin_amdgcn_s_barrier();
  __builtin_amdgcn_sched_barrier(0);
}

// Phase 1: Zx[b][col][t] = bias[col] + sum_k x[b,t,k] * Wx[k][col]
__global__ __launch_bounds__(512)
void zx_kernel(const float* __restrict__ x, const float* __restrict__ Wx,
               const float* __restrict__ bias, float* __restrict__ Zx,
               int tbase, int ct) {
  const int j = threadIdx.x;
  const int nt = ct / P1_ROWS;
  const int tblk = blockIdx.x % nt;
  const int b = blockIdx.x / nt;
  const int t0 = tblk * P1_ROWS;

  __shared__ float xsT[D_ * P1_ROWS];  // transposed: [k][r]

  const float* xp = x + ((size_t)b * T_ + tbase + t0) * D_;
  {
    int e = j * 8;
    int r = e >> 7;
    int k = e & 127;
    float4 v0 = *(const float4*)(xp + e);
    float4 v1 = *(const float4*)(xp + e + 4);
    xsT[(k + 0) * P1_ROWS + r] = v0.x;
    xsT[(k + 1) * P1_ROWS + r] = v0.y;
    xsT[(k + 2) * P1_ROWS + r] = v0.z;
    xsT[(k + 3) * P1_ROWS + r] = v0.w;
    xsT[(k + 4) * P1_ROWS + r] = v1.x;
    xsT[(k + 5) * P1_ROWS + r] = v1.y;
    xsT[(k + 6) * P1_ROWS + r] = v1.z;
    xsT[(k + 7) * P1_ROWS + r] = v1.w;
  }
  __syncthreads();

  const float bj = bias[j];
  float acc[P1_ROWS];
#pragma unroll
  for (int r = 0; r < P1_ROWS; ++r) acc[r] = bj;

  const float* wp = Wx + j;
  float w = wp[0];
#pragma unroll 2
  for (int k = 0; k < D_; ++k) {
    float wn = (k + 1 < D_) ? wp[(size_t)(k + 1) * G4_] : 0.f;
    const float4* xr = (const float4*)(xsT + k * P1_ROWS);
#pragma unroll
    for (int r4 = 0; r4 < P1_ROWS / 4; ++r4) {
      float4 xv = xr[r4];
      acc[4 * r4 + 0] += xv.x * w;
      acc[4 * r4 + 1] += xv.y * w;
      acc[4 * r4 + 2] += xv.z * w;
      acc[4 * r4 + 3] += xv.w * w;
    }
    w = wn;
  }

  float* zp = Zx + ((size_t)b * G4_ + j) * ct + t0;  // [b][col][t], t-contiguous
#pragma unroll
  for (int q = 0; q < P1_ROWS / 4; ++q)
    ((float4*)zp)[q] = make_float4(acc[4 * q], acc[4 * q + 1], acc[4 * q + 2], acc[4 * q + 3]);
}

// Phase 2: serial recurrence via f16 MFMA. One block (8 waves) per batch.
// Wave w owns u in [16w, 16w+16); its 4 N-tiles are the 4 gates of those u.
// A-frag = h broadcast (all 16 rows identical) -> any C row is z.
// Lane (col = lane&15) holds i,f,g,o of its u in acc0..acc3 -> lane-local cell.
// R3 body (fresh accs, depth-4 chains) + lgkmcnt-only barrier (no vmcnt drain).
__global__ __launch_bounds__(512)
void lstm_kernel(const float* __restrict__ Zx, const float* __restrict__ Wh,
                 float* __restrict__ out, float* __restrict__ state,
                 int tbase, int ct, int first) {
  const int j = threadIdx.x;
  const int b = blockIdx.x;
  const int w = j >> 6;
  const int lane = j & 63;
  const int l4 = lane & 15;
  const int kg = lane >> 4;       // k-group 0..3
  const int u = w * 16 + l4;      // duplicated across kg groups

  // B fragments: Wh[k][col], col = g*128+u, k = kt*32 + kg*8 + e (f32 -> f16)
  f16x8 bf[4][4];
#pragma unroll
  for (int g = 0; g < 4; ++g)
#pragma unroll
    for (int kt = 0; kt < 4; ++kt) {
      f16x8 v;
#pragma unroll
      for (int e = 0; e < 8; ++e)
        v[e] = (_Float16)Wh[(size_t)(kt * 32 + kg * 8 + e) * G4_ + g * U_ + u];
      bf[g][kt] = v;
    }

  __shared__ alignas(16) _Float16 hbuf[2][U_];  // double-buffered h (f16)

  float c_state = 0.f, h0 = 0.f;
  if (!first) {
    h0 = state[b * 2 * U_ + u];
    c_state = state[b * 2 * U_ + U_ + u];
  }
  if (kg == 0) hbuf[0][u] = (_Float16)h0;
  __syncthreads();

  const float4* zq0 = (const float4*)(Zx + ((size_t)b * G4_ + 0 * U_ + u) * ct);
  const float4* zq1 = (const float4*)(Zx + ((size_t)b * G4_ + 1 * U_ + u) * ct);
  const float4* zq2 = (const float4*)(Zx + ((size_t)b * G4_ + 2 * U_ + u) * ct);
  const float4* zq3 = (const float4*)(Zx + ((size_t)b * G4_ + 3 * U_ + u) * ct);

  float4 zc0 = zq0[0], zc1 = zq1[0], zc2 = zq2[0], zc3 = zq3[0];
  float hlast = h0;
  float* outp = out + ((size_t)tbase * B_ + b) * U_ + u;

  for (int tt = 0; tt < ct; tt += 4) {
    // group prefetch: issued here, first barrier crossed ~1 step later with
    // the load still in flight; consumed next group (~4 steps later).
    float4 zn0, zn1, zn2, zn3;
    if (tt + 4 < ct) {
      const int nq = (tt >> 2) + 1;
      zn0 = zq0[nq]; zn1 = zq1[nq]; zn2 = zq2[nq]; zn3 = zq3[nq];
    } else {
      zn0 = zn1 = zn2 = zn3 = make_float4(0.f, 0.f, 0.f, 0.f);
    }
#pragma unroll
    for (int s = 0; s < 4; ++s) {
      const int t = tt + s;
      const int cur = t & 1;
      const float zi0 = (s == 0) ? zc0.x : (s == 1) ? zc0.y : (s == 2) ? zc0.z : zc0.w;
      const float zi1 = (s == 0) ? zc1.x : (s == 1) ? zc1.y : (s == 2) ? zc1.z : zc1.w;
      const float zi2 = (s == 0) ? zc2.x : (s == 1) ? zc2.y : (s == 2) ? zc2.z : zc2.w;
      const float zi3 = (s == 0) ? zc3.x : (s == 1) ? zc3.y : (s == 2) ? zc3.z : zc3.w;

      // A-frags: broadcast h slice per k-group (16B per kt)
      const f16x8* hp = (const f16x8*)hbuf[cur];
      f16x8 a0 = hp[0 * 4 + kg];
      f16x8 a1 = hp[1 * 4 + kg];
      f16x8 a2 = hp[2 * 4 + kg];
      f16x8 a3 = hp[3 * 4 + kg];

      f32x4 acc0 = {zi0, zi0, zi0, zi0};
      f32x4 acc1 = {zi1, zi1, zi1, zi1};
      f32x4 acc2 = {zi2, zi2, zi2, zi2};
      f32x4 acc3 = {zi3, zi3, zi3, zi3};
      // kt-outer ordering interleaves the 4 independent chains (depth 4 each)
      acc0 = __builtin_amdgcn_mfma_f32_16x16x32_f16(a0, bf[0][0], acc0, 0, 0, 0);
      acc1 = __builtin_amdgcn_mfma_f32_16x16x32_f16(a0, bf[1][0], acc1, 0, 0, 0);
      acc2 = __builtin_amdgcn_mfma_f32_16x16x32_f16(a0, bf[2][0], acc2, 0, 0, 0);
      acc3 = __builtin_amdgcn_mfma_f32_16x16x32_f16(a0, bf[3][0], acc3, 0, 0, 0);
      acc0 = __builtin_amdgcn_mfma_f32_16x16x32_f16(a1, bf[0][1], acc0, 0, 0, 0);
      acc1 = __builtin_amdgcn_mfma_f32_16x16x32_f16(a1, bf[1][1], acc1, 0, 0, 0);
      acc2 = __builtin_amdgcn_mfma_f32_16x16x32_f16(a1, bf[2][1], acc2, 0, 0, 0);
      acc3 = __builtin_amdgcn_mfma_f32_16x16x32_f16(a1, bf[3][1], acc3, 0, 0, 0);
      acc0 = __builtin_amdgcn_mfma_f32_16x16x32_f16(a2, bf[0][2], acc0, 0, 0, 0);
      acc1 = __builtin_amdgcn_mfma_f32_16x16x32_f16(a2, bf[1][2], acc1, 0, 0, 0);
      acc2 = __builtin_amdgcn_mfma_f32_16x16x32_f16(a2, bf[2][2], acc2, 0, 0, 0);
      acc3 = __builtin_amdgcn_mfma_f32_16x16x32_f16(a2, bf[3][2], acc3, 0, 0, 0);
      acc0 = __builtin_amdgcn_mfma_f32_16x16x32_f16(a3, bf[0][3], acc0, 0, 0, 0);
      acc1 = __builtin_amdgcn_mfma_f32_16x16x32_f16(a3, bf[1][3], acc1, 0, 0, 0);
      acc2 = __builtin_amdgcn_mfma_f32_16x16x32_f16(a3, bf[2][3], acc2, 0, 0, 0);
      acc3 = __builtin_amdgcn_mfma_f32_16x16x32_f16(a3, bf[3][3], acc3, 0, 0, 0);

      float i_ = sigf(acc0[0]);
      float f_ = sigf(acc1[0]);
      float g_ = tanhf_(acc2[0]);
      float o_ = sigf(acc3[0]);
      c_state = fmaf(f_, c_state, i_ * g_);
      float hn = o_ * tanhf_(c_state);
      hlast = hn;

      if (kg == 0) {
        outp[(size_t)t * B_ * U_] = hn;
        hbuf[cur ^ 1][u] = (_Float16)hn;
      }
      lds_barrier();  // lgkmcnt(0) + s_barrier; vmem stays in flight
    }
    zc0 = zn0; zc1 = zn1; zc2 = zn2; zc3 = zn3;
  }

  if (kg == 0) {
    state[b * 2 * U_ + u] = hlast;
    state[b * 2 * U_ + U_ + u] = c_state;
  }
}

extern "C" void kernel_launch(void* const* d_in, const int* in_sizes, int n_in,
                              void* d_out, int out_size, void* d_ws, size_t ws_size,
                              hipStream_t stream) {
  const float* x = (const float*)d_in[0];
  const float* Wx = (const float*)d_in[1];
  const float* Wh = (const float*)d_in[2];
  const float* bias = (const float*)d_in[3];
  float* out = (float*)d_out;

  // ws layout: [0,32KB) = h/c carry state, rest = Zx chunk buffer
  float* state = (float*)d_ws;
  float* zx = (float*)((char*)d_ws + 32768);
  size_t avail = ws_size > 32768 ? ws_size - 32768 : 0;
  size_t per_t = (size_t)B_ * G4_ * sizeof(float);  // 64 KB per timestep
  long maxct = (long)(avail / per_t);
  int ct;
  if (maxct >= T_) ct = T_;
  else {
    ct = (int)((maxct / P1_ROWS) * P1_ROWS);
    if (ct < P1_ROWS) ct = P1_ROWS;
  }

  for (int tb = 0; tb < T_; tb += ct) {
    int cur = (T_ - tb < ct) ? (T_ - tb) : ct;
    zx_kernel<<<dim3(B_ * (cur / P1_ROWS)), 512, 0, stream>>>(x, Wx, bias, zx, tb, cur);
    lstm_kernel<<<dim3(B_), 512, 0, stream>>>(zx, Wh, out, state, tb, cur, tb == 0 ? 1 : 0);
  }
}